// Round 2
// baseline (1419.580 us; speedup 1.0000x reference)
//
#include <hip/hip_runtime.h>
#include <cstdint>

// ---------------------------------------------------------------------------
// MNISTSort2Net: conv1+pool -> conv2+pool -> fc1+relu -> fc2+softmax,
// then JAX-threefry categorical sampling (partitionable scheme), masked
// histograms, and scalar MSE.
//
// RNG scheme: jax_threefry_partitionable == True (JAX >= 0.4.36 default).
//   split(key(42)):  ka = TF((0,42),(0,0)), kb = TF((0,42),(0,1))  (both words)
//   random_bits(key, 32, shape): bits[i] = o0 ^ o1 of TF(key, (hi(i)=0, lo(i)=i))
// Fallback (if verification misses by ~1e-4): legacy scheme pairs counters
// (i, i+size/2) and uses o0 / o1 separately; split uses iota(4) odd/even.
// ---------------------------------------------------------------------------

__host__ __device__ __forceinline__ void tf2x32(uint32_t k0, uint32_t k1,
                                                uint32_t x0, uint32_t x1,
                                                uint32_t& o0, uint32_t& o1) {
  const uint32_t ks2 = k0 ^ k1 ^ 0x1BD11BDAu;
#define TF_R(r) { x0 += x1; x1 = (x1 << (r)) | (x1 >> (32 - (r))); x1 ^= x0; }
  x0 += k0; x1 += k1;
  TF_R(13) TF_R(15) TF_R(26) TF_R(6)
  x0 += k1;  x1 += ks2 + 1u;
  TF_R(17) TF_R(29) TF_R(16) TF_R(24)
  x0 += ks2; x1 += k0 + 2u;
  TF_R(13) TF_R(15) TF_R(26) TF_R(6)
  x0 += k0;  x1 += k1 + 3u;
  TF_R(17) TF_R(29) TF_R(16) TF_R(24)
  x0 += k1;  x1 += ks2 + 4u;
  TF_R(13) TF_R(15) TF_R(26) TF_R(6)
  x0 += ks2; x1 += k0 + 5u;
#undef TF_R
  o0 = x0; o1 = x1;
}

__device__ __forceinline__ uint32_t rb32(uint32_t k0, uint32_t k1, uint32_t idx) {
  uint32_t a, b;
  tf2x32(k0, k1, 0u, idx, a, b);   // hi word of linear index is 0 (size < 2^32)
  return a ^ b;                    // partitionable 32-bit combine
}

// u = bitcast((bits>>9)|0x3f800000)-1 in [0,1); JAX's uniform(minval=tiny)
// is u*(1-tiny)+tiny == u+tiny in fp32, == max(u,tiny) for representable u.
__device__ __forceinline__ float neg_log_unif(uint32_t bits) {
  float u = __uint_as_float((bits >> 9) | 0x3f800000u) - 1.0f;
  u = fmaxf(u, 1.17549435e-38f);
  return -__logf(u);               // Exp(1) draw; argmin(e/p) == categorical
}

// ---------------------------------------------------------------------------
// Kernel A: fused conv1(1->32,5x5)+maxpool2 + conv2(32->64,5x5)+maxpool2.
// One image per block (256 threads). Intermediate stays in LDS.
// Output: pooled2[img][oc*16 + ph*4 + pw]  (matches reshape(B,-1) order).
// No relu on convs (reference has none).
// ---------------------------------------------------------------------------
__global__ __launch_bounds__(256) void conv_fused(
    const float* __restrict__ aimg, const float* __restrict__ bimg,
    const float* __restrict__ w1, const float* __restrict__ b1,
    const float* __restrict__ w2, const float* __restrict__ b2,
    float* __restrict__ pooled2, int B) {
  __shared__ alignas(16) float img[784];
  __shared__ alignas(16) float w1s[800];
  __shared__ float b1s[32];
  __shared__ alignas(16) float buf1[32 * 144];   // [ic][ph*12+pw], rows 16B-aligned
  __shared__ alignas(16) float w2s[64 * 101];    // 4-ic chunk of conv2 w, pad 101
  __shared__ float b2s[64];

  const int t = threadIdx.x;
  const int im = blockIdx.x;
  const float* src = (im < B) ? (aimg + (size_t)im * 784)
                              : (bimg + (size_t)(im - B) * 784);
  for (int i = t; i < 784; i += 256) img[i] = src[i];
  for (int i = t; i < 800; i += 256) w1s[i] = w1[i];
  if (t < 32) b1s[t] = b1[t];
  if (t >= 64 && t < 128) b2s[t - 64] = b2[t - 64];
  __syncthreads();

  // ---- conv1 + pool: thread t -> oc=t>>3 (32), sub=t&7; 18 pooled px each
  {
    const int oc = t >> 3, sub = t & 7;
    float w[25];
#pragma unroll
    for (int k = 0; k < 25; ++k) w[k] = w1s[oc * 25 + k];
    const float bias = b1s[oc];
#pragma unroll 1
    for (int j = 0; j < 18; ++j) {
      const int p = sub + (j << 3);          // 0..143
      const int ph = p / 12, pw = p - ph * 12;
      const int y0 = ph << 1, x0 = pw << 1;
      float patch[36];
#pragma unroll
      for (int r = 0; r < 6; ++r)
#pragma unroll
        for (int c = 0; c < 6; ++c)
          patch[r * 6 + c] = img[(y0 + r) * 28 + x0 + c];
      float m = -3.0e38f;
#pragma unroll
      for (int dy = 0; dy < 2; ++dy)
#pragma unroll
        for (int dx = 0; dx < 2; ++dx) {
          float acc = 0.f;
#pragma unroll
          for (int kh = 0; kh < 5; ++kh)
#pragma unroll
            for (int kw = 0; kw < 5; ++kw)
              acc += w[kh * 5 + kw] * patch[(dy + kh) * 6 + (dx + kw)];
          m = fmaxf(m, acc);
        }
      buf1[oc * 144 + p] = m + bias;         // bias after max (equivalent)
    }
  }
  __syncthreads();

  // ---- conv2 + pool: thread t -> oc=t>>2 (64), sub=t&3 = pooled row ph.
  // Per ic: load the 6 needed conv1 rows ONCE (16B-aligned, 3x ds_read_b128
  // each), then all 10 (kh,r) taps reuse registers. 18 b128 vs 120 b32 reads.
  const int oc2 = t >> 2, sub2 = t & 3;
  float acc2[2][8];
#pragma unroll
  for (int r = 0; r < 2; ++r)
#pragma unroll
    for (int c = 0; c < 8; ++c) acc2[r][c] = 0.f;

#pragma unroll 1
  for (int icc = 0; icc < 8; ++icc) {        // 8 chunks of 4 input channels
    __syncthreads();
    for (int i = t; i < 6400; i += 256) {    // stage w2[:, icc*4:+4, :, :]
      const int o = i / 100, idx = i - o * 100;
      w2s[o * 101 + idx] = w2[o * 800 + icc * 100 + idx];
    }
    __syncthreads();
#pragma unroll 1
    for (int ici = 0; ici < 4; ++ici) {
      const int ic = icc * 4 + ici;
      float w[25];
#pragma unroll
      for (int k = 0; k < 25; ++k) w[k] = w2s[oc2 * 101 + ici * 25 + k];
      const float* bp = &buf1[ic * 144];
      float rows[6][12];                     // conv1 rows 2*sub2 .. 2*sub2+5
#pragma unroll
      for (int j = 0; j < 6; ++j) {
        const float4* rp = (const float4*)(bp + (2 * sub2 + j) * 12);
        *(float4*)&rows[j][0] = rp[0];
        *(float4*)&rows[j][4] = rp[1];
        *(float4*)&rows[j][8] = rp[2];
      }
#pragma unroll
      for (int kh = 0; kh < 5; ++kh)
#pragma unroll
        for (int r = 0; r < 2; ++r) {
          const float* in = &rows[r + kh][0];
#pragma unroll
          for (int cw = 0; cw < 8; ++cw)
#pragma unroll
            for (int kw = 0; kw < 5; ++kw)
              acc2[r][cw] += w[kh * 5 + kw] * in[cw + kw];
        }
    }
  }
  const float bias2 = b2s[oc2];
  float4 res;
  float* rp = (float*)&res;
#pragma unroll
  for (int pw = 0; pw < 4; ++pw) {
    const float m = fmaxf(fmaxf(acc2[0][2 * pw], acc2[0][2 * pw + 1]),
                          fmaxf(acc2[1][2 * pw], acc2[1][2 * pw + 1]));
    rp[pw] = m + bias2;
  }
  // oc2*16 + sub2*4 == 4*t  -> coalesced float4 store
  *(float4*)&pooled2[(size_t)im * 1024 + t * 4] = res;
}

// ---------------------------------------------------------------------------
// Kernel C: fc1 GEMM  out = relu(A[8192,1024] @ W[1024,1024] + b)
// 128x128 tile, BK=16, 256 threads, 8x8 per thread.
// ---------------------------------------------------------------------------
__global__ __launch_bounds__(256) void fc1_gemm(const float* __restrict__ A,
                                                const float* __restrict__ W,
                                                const float* __restrict__ bias,
                                                float* __restrict__ out) {
  __shared__ alignas(16) float As[16][128];   // [k][m] (transposed)
  __shared__ alignas(16) float Bs[16][128];   // [k][n]
  const int t = threadIdx.x;
  const int bx = blockIdx.x & 7, by = blockIdx.x >> 3;
  const int m0 = by * 128, n0 = bx * 128;
  const int tx = t & 15, ty = t >> 4;
  const int arow = t >> 2, akq = t & 3;
  const int brow = t >> 4, bnq = t & 15;
  float acc[8][8];
#pragma unroll
  for (int i = 0; i < 8; ++i)
#pragma unroll
    for (int j = 0; j < 8; ++j) acc[i][j] = 0.f;

  for (int k0 = 0; k0 < 1024; k0 += 16) {
    const float4 av0 = *(const float4*)&A[(size_t)(m0 + arow) * 1024 + k0 + akq * 4];
    const float4 av1 = *(const float4*)&A[(size_t)(m0 + arow + 64) * 1024 + k0 + akq * 4];
    const float4 bv0 = *(const float4*)&W[(size_t)(k0 + brow) * 1024 + n0 + bnq * 8];
    const float4 bv1 = *(const float4*)&W[(size_t)(k0 + brow) * 1024 + n0 + bnq * 8 + 4];
    __syncthreads();
    As[akq * 4 + 0][arow] = av0.x;
    As[akq * 4 + 1][arow] = av0.y;
    As[akq * 4 + 2][arow] = av0.z;
    As[akq * 4 + 3][arow] = av0.w;
    As[akq * 4 + 0][arow + 64] = av1.x;
    As[akq * 4 + 1][arow + 64] = av1.y;
    As[akq * 4 + 2][arow + 64] = av1.z;
    As[akq * 4 + 3][arow + 64] = av1.w;
    *(float4*)&Bs[brow][bnq * 8] = bv0;
    *(float4*)&Bs[brow][bnq * 8 + 4] = bv1;
    __syncthreads();
#pragma unroll
    for (int kk = 0; kk < 16; ++kk) {
      float a[8], b[8];
      *(float4*)&a[0] = *(const float4*)&As[kk][ty * 8];
      *(float4*)&a[4] = *(const float4*)&As[kk][ty * 8 + 4];
      *(float4*)&b[0] = *(const float4*)&Bs[kk][tx * 8];
      *(float4*)&b[4] = *(const float4*)&Bs[kk][tx * 8 + 4];
#pragma unroll
      for (int i = 0; i < 8; ++i)
#pragma unroll
        for (int j = 0; j < 8; ++j) acc[i][j] += a[i] * b[j];
    }
  }
#pragma unroll
  for (int i = 0; i < 8; ++i) {
    const size_t row = (size_t)(m0 + ty * 8 + i) * 1024 + n0 + tx * 8;
    float4 o0, o1;
    float* p0 = (float*)&o0; float* p1 = (float*)&o1;
#pragma unroll
    for (int j = 0; j < 4; ++j) {
      p0[j] = fmaxf(acc[i][j] + bias[n0 + tx * 8 + j], 0.f);
      p1[j] = fmaxf(acc[i][4 + j] + bias[n0 + tx * 8 + 4 + j], 0.f);
    }
    *(float4*)&out[row] = o0;
    *(float4*)&out[row + 4] = o1;
  }
}

// ---------------------------------------------------------------------------
// Kernel D: fc2 (1024->10) + softmax. One wave per row.
// Stores distrs (for MSE) and invp = sum/exp (for argmin sampling).
// ---------------------------------------------------------------------------
__global__ __launch_bounds__(64) void fc2_softmax(const float* __restrict__ X,
                                                  const float* __restrict__ W,
                                                  const float* __restrict__ bias,
                                                  float* __restrict__ distrs,
                                                  float* __restrict__ invp) {
  const int row = blockIdx.x, l = threadIdx.x;
  const float* x = X + (size_t)row * 1024;
  float acc[10];
#pragma unroll
  for (int c = 0; c < 10; ++c) acc[c] = 0.f;
  for (int k = l; k < 1024; k += 64) {
    const float xv = x[k];
    const float* wr = W + (size_t)k * 10;
#pragma unroll
    for (int c = 0; c < 10; ++c) acc[c] += xv * wr[c];
  }
#pragma unroll
  for (int c = 0; c < 10; ++c) {
    float v = acc[c];
#pragma unroll
    for (int off = 32; off > 0; off >>= 1) v += __shfl_xor(v, off, 64);
    acc[c] = v;
  }
  float z[10], m = -3.0e38f;
#pragma unroll
  for (int c = 0; c < 10; ++c) { z[c] = acc[c] + bias[c]; m = fmaxf(m, z[c]); }
  float s = 0.f, e[10];
#pragma unroll
  for (int c = 0; c < 10; ++c) { e[c] = __expf(z[c] - m); s += e[c]; }
  if (l < 10) {
    distrs[(size_t)row * 10 + l] = e[l] / s;
    invp[(size_t)row * 10 + l] = s / e[l];   // inf if e underflows: cat never wins (matches -inf logit)
  }
}

// ---------------------------------------------------------------------------
// Kernel E: categorical sampling (threefry) + masked hist + per-row MSE part.
// One block per batch row; 512 threads; n_samples read from device scalar.
// b_pred is one-hot(y) when total>0 (mask forces b_s==y), so only hist_a+total.
// ---------------------------------------------------------------------------
__global__ __launch_bounds__(512) void sample_hist_mse(
    const float* __restrict__ distrs, const float* __restrict__ invp,
    const int* __restrict__ y, const int* __restrict__ nsamp,
    float* __restrict__ out, int B,
    uint32_t ka0, uint32_t ka1, uint32_t kb0, uint32_t kb1) {
  const int brow = blockIdx.x, tid = threadIdx.x;
  __shared__ float ipa[10], ipb[10], part[10];
  __shared__ int ha[10], tot;
  if (tid < 10) { ipa[tid] = invp[(size_t)brow * 10 + tid]; ha[tid] = 0; }
  else if (tid < 20) ipb[tid - 10] = invp[(size_t)(B + brow) * 10 + (tid - 10)];
  else if (tid == 20) tot = 0;
  __syncthreads();
  const int yy = y[brow];
  const int S = nsamp[0];
  for (int s0 = 0; s0 < S; s0 += 512) {
    const int s = s0 + tid;
    if (s >= S) break;
    const uint32_t base = ((uint32_t)s * (uint32_t)B + (uint32_t)brow) * 10u; // (S,B,10)
    float bestA = __builtin_inff(), bestB = __builtin_inff();
    int as = 0, bs = 0;
#pragma unroll
    for (int c = 0; c < 10; ++c) {
      const float va = neg_log_unif(rb32(ka0, ka1, base + (uint32_t)c)) * ipa[c];
      if (va < bestA) { bestA = va; as = c; }   // strict < keeps first index (argmax tie rule)
      const float vb = neg_log_unif(rb32(kb0, kb1, base + (uint32_t)c)) * ipb[c];
      if (vb < bestB) { bestB = vb; bs = c; }
    }
    if (bs == yy && as >= bs) { atomicAdd(&ha[as], 1); atomicAdd(&tot, 1); }
  }
  __syncthreads();
  if (tid < 10) {
    const int tc = tot;
    const float denom = fmaxf((float)tc, 1.0f);
    const float ap = (tc > 0) ? (float)ha[tid] / denom : 0.0f;
    const float bp = (tc > 0 && tid == yy) ? ((float)tc / denom) : 0.0f;
    const float da = distrs[(size_t)brow * 10 + tid] - ap;
    const float db = distrs[(size_t)(B + brow) * 10 + tid] - bp;
    part[tid] = da * da + db * db;
  }
  __syncthreads();
  if (tid == 0) {
    float sum = 0.f;
#pragma unroll
    for (int i = 0; i < 10; ++i) sum += part[i];
    atomicAdd(out, sum);
  }
}

__global__ void finalize_mean(float* out, float n) { out[0] = out[0] / n; }

// ---------------------------------------------------------------------------
extern "C" void kernel_launch(void* const* d_in, const int* in_sizes, int n_in,
                              void* d_out, int out_size, void* d_ws, size_t ws_size,
                              hipStream_t stream) {
  (void)n_in; (void)out_size; (void)ws_size;
  const float* a_imgs = (const float*)d_in[0];
  const float* b_imgs = (const float*)d_in[1];
  const float* c1w = (const float*)d_in[2];
  const float* c1b = (const float*)d_in[3];
  const float* c2w = (const float*)d_in[4];
  const float* c2b = (const float*)d_in[5];
  const float* f1w = (const float*)d_in[6];
  const float* f1b = (const float*)d_in[7];
  const float* f2w = (const float*)d_in[8];
  const float* f2b = (const float*)d_in[9];
  const int* y = (const int*)d_in[10];
  const int* nsamp = (const int*)d_in[11];

  const int B = in_sizes[0] / 784;   // 4096
  const int R = 2 * B;               // 8192 images through the net

  float* pooled2 = (float*)d_ws;                       // [R][1024]
  float* fc1out  = pooled2 + (size_t)R * 1024;         // [R][1024]
  float* distrs  = fc1out + (size_t)R * 1024;          // [R][10]
  float* invp    = distrs + (size_t)R * 10;            // [R][10]

  // jax.random.split(jax.random.key(42)) under partitionable threefry
  uint32_t ka0, ka1, kb0, kb1;
  tf2x32(0u, 42u, 0u, 0u, ka0, ka1);
  tf2x32(0u, 42u, 0u, 1u, kb0, kb1);

  hipMemsetAsync(d_out, 0, sizeof(float), stream);
  conv_fused<<<R, 256, 0, stream>>>(a_imgs, b_imgs, c1w, c1b, c2w, c2b, pooled2, B);
  fc1_gemm<<<(R / 128) * 8, 256, 0, stream>>>(pooled2, f1w, f1b, fc1out);
  fc2_softmax<<<R, 64, 0, stream>>>(fc1out, f2w, f2b, distrs, invp);
  sample_hist_mse<<<B, 512, 0, stream>>>(distrs, invp, y, nsamp, (float*)d_out, B,
                                         ka0, ka1, kb0, kb1);
  finalize_mean<<<1, 1, 0, stream>>>((float*)d_out, (float)R * 10.0f);
}

// Round 3
// 897.345 us; speedup vs baseline: 1.5820x; 1.5820x over previous
//
#include <hip/hip_runtime.h>
#include <cstdint>

typedef __attribute__((ext_vector_type(8))) short short8;
typedef __attribute__((ext_vector_type(4))) float f32x4;

// ---------------------------------------------------------------------------
// threefry (partitionable scheme) -- verified bit-exact in round 2 (absmax 0.0)
// ---------------------------------------------------------------------------
__host__ __device__ __forceinline__ void tf2x32(uint32_t k0, uint32_t k1,
                                                uint32_t x0, uint32_t x1,
                                                uint32_t& o0, uint32_t& o1) {
  const uint32_t ks2 = k0 ^ k1 ^ 0x1BD11BDAu;
#define TF_R(r) { x0 += x1; x1 = (x1 << (r)) | (x1 >> (32 - (r))); x1 ^= x0; }
  x0 += k0; x1 += k1;
  TF_R(13) TF_R(15) TF_R(26) TF_R(6)
  x0 += k1;  x1 += ks2 + 1u;
  TF_R(17) TF_R(29) TF_R(16) TF_R(24)
  x0 += ks2; x1 += k0 + 2u;
  TF_R(13) TF_R(15) TF_R(26) TF_R(6)
  x0 += k0;  x1 += k1 + 3u;
  TF_R(17) TF_R(29) TF_R(16) TF_R(24)
  x0 += k1;  x1 += ks2 + 4u;
  TF_R(13) TF_R(15) TF_R(26) TF_R(6)
  x0 += ks2; x1 += k0 + 5u;
#undef TF_R
  o0 = x0; o1 = x1;
}

__device__ __forceinline__ uint32_t rb32(uint32_t k0, uint32_t k1, uint32_t idx) {
  uint32_t a, b;
  tf2x32(k0, k1, 0u, idx, a, b);
  return a ^ b;
}

__device__ __forceinline__ float neg_log_unif(uint32_t bits) {
  float u = __uint_as_float((bits >> 9) | 0x3f800000u) - 1.0f;
  u = fmaxf(u, 1.17549435e-38f);
  return -__logf(u);
}

// bf16 split helpers (RNE)
__device__ __host__ __forceinline__ ushort f2bf(float f) {
  uint32_t x;
  __builtin_memcpy(&x, &f, 4);
  return (ushort)((x + 0x7fffu + ((x >> 16) & 1u)) >> 16);
}
__device__ __forceinline__ float bf2f(ushort h) {
  return __uint_as_float(((uint32_t)h) << 16);
}

// ---------------------------------------------------------------------------
// Pre-split conv2 weights into bf16 hi/lo (native [oc][ic*25+tap] k-order).
// ---------------------------------------------------------------------------
__global__ __launch_bounds__(256) void convert_w2(const float* __restrict__ w,
                                                  ushort* __restrict__ wh,
                                                  ushort* __restrict__ wl, int n) {
  const int i = blockIdx.x * 256 + threadIdx.x;
  if (i < n) {
    const float f = w[i];
    const ushort h = f2bf(f);
    wh[i] = h;
    wl[i] = f2bf(f - bf2f(h));
  }
}

// ---------------------------------------------------------------------------
// Kernel A: conv1(5x5)+pool on VALU, conv2(5x5) as split-bf16 MFMA implicit
// GEMM (D[px64][oc64], K=800, 25 chunks of 32), pool, coalesced store.
// One image per block, 256 threads (4 waves). LDS 39296 B -> 4 blocks/CU.
// ---------------------------------------------------------------------------
__global__ __launch_bounds__(256, 4) void conv_fused(
    const float* __restrict__ aimg, const float* __restrict__ bimg,
    const float* __restrict__ w1, const float* __restrict__ b1,
    const ushort* __restrict__ w2h, const ushort* __restrict__ w2l,
    const float* __restrict__ b2,
    float* __restrict__ pooled2, int B) {
  // union region: phase1 {img 784f, w1s 800f}=6336B | phase2 {4 mfma bufs}=20480B
  // | phase3 {ob 1024f}=4096B
  __shared__ __align__(16) char smem[20480];
  __shared__ float b1s[32];
  __shared__ float b2s[64];
  __shared__ __align__(16) float buf1[32 * 144];   // conv1 pooled out [ic][12*12]

  float* img = (float*)smem;                 // [784]
  float* w1s = img + 784;                    // [800]
  ushort* aH = (ushort*)smem;                // [64][40] act hi (pad 32->40)
  ushort* aL = aH + 64 * 40;                 // act lo
  ushort* wHs = aL + 64 * 40;                // [64][40] w hi
  ushort* wLs = wHs + 64 * 40;               // w lo
  float* ob = (float*)smem;                  // [1024] epilogue staging

  const int t = threadIdx.x;
  const int im = blockIdx.x;
  const float* src = (im < B) ? (aimg + (size_t)im * 784)
                              : (bimg + (size_t)(im - B) * 784);
  for (int i = t; i < 784; i += 256) img[i] = src[i];
  for (int i = t; i < 800; i += 256) w1s[i] = w1[i];
  if (t < 32) b1s[t] = b1[t];
  if (t >= 64 && t < 128) b2s[t - 64] = b2[t - 64];
  __syncthreads();

  // ---- conv1 + pool: thread t -> oc=t>>3 (32), sub=t&7; 18 pooled px each
  {
    const int oc = t >> 3, sub = t & 7;
    float w[25];
#pragma unroll
    for (int k = 0; k < 25; ++k) w[k] = w1s[oc * 25 + k];
    const float bias = b1s[oc];
#pragma unroll 1
    for (int j = 0; j < 18; ++j) {
      const int p = sub + (j << 3);          // 0..143
      const int ph = p / 12, pw = p - ph * 12;
      const int y0 = ph << 1, x0 = pw << 1;
      float patch[36];
#pragma unroll
      for (int r = 0; r < 6; ++r)
#pragma unroll
        for (int c = 0; c < 6; ++c)
          patch[r * 6 + c] = img[(y0 + r) * 28 + x0 + c];
      float m = -3.0e38f;
#pragma unroll
      for (int dy = 0; dy < 2; ++dy)
#pragma unroll
        for (int dx = 0; dx < 2; ++dx) {
          float acc = 0.f;
#pragma unroll
          for (int kh = 0; kh < 5; ++kh)
#pragma unroll
            for (int kw = 0; kw < 5; ++kw)
              acc += w[kh * 5 + kw] * patch[(dy + kh) * 6 + (dx + kw)];
          m = fmaxf(m, acc);
        }
      buf1[oc * 144 + p] = m + bias;
    }
  }

  // ---- conv2 via MFMA: act A[px][k], weights B[k][oc], 16x16x32 frags.
  const int l = t & 63;            // lane
  const int wv = t >> 6;           // wave id = px-tile (rows 16wv..16wv+15)
  const int gi = l >> 4, ii = l & 15;
  const int px = t & 63, kg = t >> 6;       // im2col build mapping
  const int rr = px >> 3, cc = px & 7;
  const int ocs = t >> 2, qq = t & 3;       // weight staging mapping

  f32x4 acc[4];
#pragma unroll
  for (int t4 = 0; t4 < 4; ++t4) acc[t4] = (f32x4){0.f, 0.f, 0.f, 0.f};

#pragma unroll 1
  for (int kc = 0; kc < 25; ++kc) {
    __syncthreads();   // prev chunk's frag reads done (and conv1 done at kc=0)
    // stage weight chunk: [oc][32k] hi/lo, b128 in / b128 out
    *(short8*)&wHs[ocs * 40 + qq * 8] =
        *(const short8*)&w2h[ocs * 800 + kc * 32 + qq * 8];
    *(short8*)&wLs[ocs * 40 + qq * 8] =
        *(const short8*)&w2l[ocs * 800 + kc * 32 + qq * 8];
    // build act chunk (im2col from buf1): thread -> (px, 8 k's)
    union { ushort u[8]; short8 v; } hv, lv;
#pragma unroll
    for (int j = 0; j < 8; ++j) {
      const int k = kc * 32 + kg * 8 + j;
      const int ic = (k * 1311) >> 15;        // k/25 for k<1300
      const int tap = k - ic * 25;
      const int kh = (tap * 205) >> 10;       // tap/5 for tap<25
      const int kw = tap - kh * 5;
      const float f = buf1[ic * 144 + (rr + kh) * 12 + (cc + kw)];
      const ushort h = f2bf(f);
      hv.u[j] = h;
      lv.u[j] = f2bf(f - bf2f(h));
    }
    *(short8*)&aH[px * 40 + kg * 8] = hv.v;
    *(short8*)&aL[px * 40 + kg * 8] = lv.v;
    __syncthreads();
    // MFMA: A row = 16wv+ii, 8k at 8*gi; B col-tile t4
    const short8 ah = *(const short8*)&aH[(16 * wv + ii) * 40 + 8 * gi];
    const short8 al = *(const short8*)&aL[(16 * wv + ii) * 40 + 8 * gi];
#pragma unroll
    for (int t4 = 0; t4 < 4; ++t4) {
      const short8 bh = *(const short8*)&wHs[(16 * t4 + ii) * 40 + 8 * gi];
      const short8 bl = *(const short8*)&wLs[(16 * t4 + ii) * 40 + 8 * gi];
      acc[t4] = __builtin_amdgcn_mfma_f32_16x16x32_bf16(ah, bh, acc[t4], 0, 0, 0);
      acc[t4] = __builtin_amdgcn_mfma_f32_16x16x32_bf16(al, bh, acc[t4], 0, 0, 0);
      acc[t4] = __builtin_amdgcn_mfma_f32_16x16x32_bf16(ah, bl, acc[t4], 0, 0, 0);
    }
  }
  __syncthreads();

  // pool 2x2 + bias: D row m=4*gi+reg -> px=16wv+m (conv rows 2wv,2wv+1).
  // horiz pair in-lane (regs 2j,2j+1); vert pair lane l <-> l^32 (gi^2).
#pragma unroll
  for (int t4 = 0; t4 < 4; ++t4) {
#pragma unroll
    for (int j = 0; j < 2; ++j) {
      const float hm = fmaxf(acc[t4][2 * j], acc[t4][2 * j + 1]);
      const float vm = fmaxf(hm, __shfl_xor(hm, 32));
      if (l < 32)   // gi 0,1 hold pooled row ph=wv, pw=2*gi+j; oc=16*t4+ii
        ob[(16 * t4 + ii) * 16 + wv * 4 + 2 * gi + j] = vm + b2s[16 * t4 + ii];
    }
  }
  __syncthreads();
  *(float4*)&pooled2[(size_t)im * 1024 + 4 * t] = *(const float4*)&ob[4 * t];
}

// ---------------------------------------------------------------------------
// Kernel C: fc1 GEMM  out = relu(A[8192,1024] @ W[1024,1024] + b)  (fp32 VALU)
// ---------------------------------------------------------------------------
__global__ __launch_bounds__(256) void fc1_gemm(const float* __restrict__ A,
                                                const float* __restrict__ W,
                                                const float* __restrict__ bias,
                                                float* __restrict__ out) {
  __shared__ alignas(16) float As[16][128];
  __shared__ alignas(16) float Bs[16][128];
  const int t = threadIdx.x;
  const int bx = blockIdx.x & 7, by = blockIdx.x >> 3;
  const int m0 = by * 128, n0 = bx * 128;
  const int tx = t & 15, ty = t >> 4;
  const int arow = t >> 2, akq = t & 3;
  const int brow = t >> 4, bnq = t & 15;
  float acc[8][8];
#pragma unroll
  for (int i = 0; i < 8; ++i)
#pragma unroll
    for (int j = 0; j < 8; ++j) acc[i][j] = 0.f;

  for (int k0 = 0; k0 < 1024; k0 += 16) {
    const float4 av0 = *(const float4*)&A[(size_t)(m0 + arow) * 1024 + k0 + akq * 4];
    const float4 av1 = *(const float4*)&A[(size_t)(m0 + arow + 64) * 1024 + k0 + akq * 4];
    const float4 bv0 = *(const float4*)&W[(size_t)(k0 + brow) * 1024 + n0 + bnq * 8];
    const float4 bv1 = *(const float4*)&W[(size_t)(k0 + brow) * 1024 + n0 + bnq * 8 + 4];
    __syncthreads();
    As[akq * 4 + 0][arow] = av0.x;
    As[akq * 4 + 1][arow] = av0.y;
    As[akq * 4 + 2][arow] = av0.z;
    As[akq * 4 + 3][arow] = av0.w;
    As[akq * 4 + 0][arow + 64] = av1.x;
    As[akq * 4 + 1][arow + 64] = av1.y;
    As[akq * 4 + 2][arow + 64] = av1.z;
    As[akq * 4 + 3][arow + 64] = av1.w;
    *(float4*)&Bs[brow][bnq * 8] = bv0;
    *(float4*)&Bs[brow][bnq * 8 + 4] = bv1;
    __syncthreads();
#pragma unroll
    for (int kk = 0; kk < 16; ++kk) {
      float a[8], b[8];
      *(float4*)&a[0] = *(const float4*)&As[kk][ty * 8];
      *(float4*)&a[4] = *(const float4*)&As[kk][ty * 8 + 4];
      *(float4*)&b[0] = *(const float4*)&Bs[kk][tx * 8];
      *(float4*)&b[4] = *(const float4*)&Bs[kk][tx * 8 + 4];
#pragma unroll
      for (int i = 0; i < 8; ++i)
#pragma unroll
        for (int j = 0; j < 8; ++j) acc[i][j] += a[i] * b[j];
    }
  }
#pragma unroll
  for (int i = 0; i < 8; ++i) {
    const size_t row = (size_t)(m0 + ty * 8 + i) * 1024 + n0 + tx * 8;
    float4 o0, o1;
    float* p0 = (float*)&o0; float* p1 = (float*)&o1;
#pragma unroll
    for (int j = 0; j < 4; ++j) {
      p0[j] = fmaxf(acc[i][j] + bias[n0 + tx * 8 + j], 0.f);
      p1[j] = fmaxf(acc[i][4 + j] + bias[n0 + tx * 8 + 4 + j], 0.f);
    }
    *(float4*)&out[row] = o0;
    *(float4*)&out[row + 4] = o1;
  }
}

// ---------------------------------------------------------------------------
// Kernel D: fc2 (1024->10) + softmax. One wave per row.
// ---------------------------------------------------------------------------
__global__ __launch_bounds__(64) void fc2_softmax(const float* __restrict__ X,
                                                  const float* __restrict__ W,
                                                  const float* __restrict__ bias,
                                                  float* __restrict__ distrs,
                                                  float* __restrict__ invp) {
  const int row = blockIdx.x, l = threadIdx.x;
  const float* x = X + (size_t)row * 1024;
  float acc[10];
#pragma unroll
  for (int c = 0; c < 10; ++c) acc[c] = 0.f;
  for (int k = l; k < 1024; k += 64) {
    const float xv = x[k];
    const float* wr = W + (size_t)k * 10;
#pragma unroll
    for (int c = 0; c < 10; ++c) acc[c] += xv * wr[c];
  }
#pragma unroll
  for (int c = 0; c < 10; ++c) {
    float v = acc[c];
#pragma unroll
    for (int off = 32; off > 0; off >>= 1) v += __shfl_xor(v, off, 64);
    acc[c] = v;
  }
  float z[10], m = -3.0e38f;
#pragma unroll
  for (int c = 0; c < 10; ++c) { z[c] = acc[c] + bias[c]; m = fmaxf(m, z[c]); }
  float s = 0.f, e[10];
#pragma unroll
  for (int c = 0; c < 10; ++c) { e[c] = __expf(z[c] - m); s += e[c]; }
  if (l < 10) {
    distrs[(size_t)row * 10 + l] = e[l] / s;
    invp[(size_t)row * 10 + l] = s / e[l];
  }
}

// ---------------------------------------------------------------------------
// Kernel E: threefry categorical + masked hist + per-row MSE partials.
// ---------------------------------------------------------------------------
__global__ __launch_bounds__(512) void sample_hist_mse(
    const float* __restrict__ distrs, const float* __restrict__ invp,
    const int* __restrict__ y, const int* __restrict__ nsamp,
    float* __restrict__ out, int B,
    uint32_t ka0, uint32_t ka1, uint32_t kb0, uint32_t kb1) {
  const int brow = blockIdx.x, tid = threadIdx.x;
  __shared__ float ipa[10], ipb[10], part[10];
  __shared__ int ha[10], tot;
  if (tid < 10) { ipa[tid] = invp[(size_t)brow * 10 + tid]; ha[tid] = 0; }
  else if (tid < 20) ipb[tid - 10] = invp[(size_t)(B + brow) * 10 + (tid - 10)];
  else if (tid == 20) tot = 0;
  __syncthreads();
  const int yy = y[brow];
  const int S = nsamp[0];
  for (int s0 = 0; s0 < S; s0 += 512) {
    const int s = s0 + tid;
    if (s >= S) break;
    const uint32_t base = ((uint32_t)s * (uint32_t)B + (uint32_t)brow) * 10u;
    float bestA = __builtin_inff(), bestB = __builtin_inff();
    int as = 0, bs = 0;
#pragma unroll
    for (int c = 0; c < 10; ++c) {
      const float va = neg_log_unif(rb32(ka0, ka1, base + (uint32_t)c)) * ipa[c];
      if (va < bestA) { bestA = va; as = c; }
      const float vb = neg_log_unif(rb32(kb0, kb1, base + (uint32_t)c)) * ipb[c];
      if (vb < bestB) { bestB = vb; bs = c; }
    }
    if (bs == yy && as >= bs) { atomicAdd(&ha[as], 1); atomicAdd(&tot, 1); }
  }
  __syncthreads();
  if (tid < 10) {
    const int tc = tot;
    const float denom = fmaxf((float)tc, 1.0f);
    const float ap = (tc > 0) ? (float)ha[tid] / denom : 0.0f;
    const float bp = (tc > 0 && tid == yy) ? ((float)tc / denom) : 0.0f;
    const float da = distrs[(size_t)brow * 10 + tid] - ap;
    const float db = distrs[(size_t)(B + brow) * 10 + tid] - bp;
    part[tid] = da * da + db * db;
  }
  __syncthreads();
  if (tid == 0) {
    float sum = 0.f;
#pragma unroll
    for (int i = 0; i < 10; ++i) sum += part[i];
    atomicAdd(out, sum);
  }
}

__global__ void finalize_mean(float* out, float n) { out[0] = out[0] / n; }

// ---------------------------------------------------------------------------
extern "C" void kernel_launch(void* const* d_in, const int* in_sizes, int n_in,
                              void* d_out, int out_size, void* d_ws, size_t ws_size,
                              hipStream_t stream) {
  (void)n_in; (void)out_size; (void)ws_size;
  const float* a_imgs = (const float*)d_in[0];
  const float* b_imgs = (const float*)d_in[1];
  const float* c1w = (const float*)d_in[2];
  const float* c1b = (const float*)d_in[3];
  const float* c2w = (const float*)d_in[4];
  const float* c2b = (const float*)d_in[5];
  const float* f1w = (const float*)d_in[6];
  const float* f1b = (const float*)d_in[7];
  const float* f2w = (const float*)d_in[8];
  const float* f2b = (const float*)d_in[9];
  const int* y = (const int*)d_in[10];
  const int* nsamp = (const int*)d_in[11];

  const int B = in_sizes[0] / 784;   // 4096
  const int R = 2 * B;               // 8192 images

  float* pooled2 = (float*)d_ws;                       // [R][1024]
  float* fc1out  = pooled2 + (size_t)R * 1024;         // [R][1024]
  float* distrs  = fc1out + (size_t)R * 1024;          // [R][10]
  float* invp    = distrs + (size_t)R * 10;            // [R][10]
  ushort* w2h    = (ushort*)(invp + (size_t)R * 10);   // [64*800] bf16 hi
  ushort* w2l    = w2h + 64 * 800;                     // [64*800] bf16 lo

  uint32_t ka0, ka1, kb0, kb1;
  tf2x32(0u, 42u, 0u, 0u, ka0, ka1);
  tf2x32(0u, 42u, 0u, 1u, kb0, kb1);

  hipMemsetAsync(d_out, 0, sizeof(float), stream);
  convert_w2<<<200, 256, 0, stream>>>(c2w, w2h, w2l, 64 * 800);
  conv_fused<<<R, 256, 0, stream>>>(a_imgs, b_imgs, c1w, c1b, w2h, w2l, c2b,
                                    pooled2, B);
  fc1_gemm<<<(R / 128) * 8, 256, 0, stream>>>(pooled2, f1w, f1b, fc1out);
  fc2_softmax<<<R, 64, 0, stream>>>(fc1out, f2w, f2b, distrs, invp);
  sample_hist_mse<<<B, 512, 0, stream>>>(distrs, invp, y, nsamp, (float*)d_out, B,
                                         ka0, ka1, kb0, kb1);
  finalize_mean<<<1, 1, 0, stream>>>((float*)d_out, (float)R * 10.0f);
}

// Round 4
// 629.376 us; speedup vs baseline: 2.2555x; 1.4258x over previous
//
#include <hip/hip_runtime.h>
#include <cstdint>

typedef __attribute__((ext_vector_type(8))) short short8;
typedef __attribute__((ext_vector_type(4))) short short4v;
typedef __attribute__((ext_vector_type(4))) float f32x4;

// ---------------------------------------------------------------------------
// threefry (partitionable scheme) -- verified bit-exact (absmax 0.0, r2/r3)
// ---------------------------------------------------------------------------
__host__ __device__ __forceinline__ void tf2x32(uint32_t k0, uint32_t k1,
                                                uint32_t x0, uint32_t x1,
                                                uint32_t& o0, uint32_t& o1) {
  const uint32_t ks2 = k0 ^ k1 ^ 0x1BD11BDAu;
#define TF_R(r) { x0 += x1; x1 = (x1 << (r)) | (x1 >> (32 - (r))); x1 ^= x0; }
  x0 += k0; x1 += k1;
  TF_R(13) TF_R(15) TF_R(26) TF_R(6)
  x0 += k1;  x1 += ks2 + 1u;
  TF_R(17) TF_R(29) TF_R(16) TF_R(24)
  x0 += ks2; x1 += k0 + 2u;
  TF_R(13) TF_R(15) TF_R(26) TF_R(6)
  x0 += k0;  x1 += k1 + 3u;
  TF_R(17) TF_R(29) TF_R(16) TF_R(24)
  x0 += k1;  x1 += ks2 + 4u;
  TF_R(13) TF_R(15) TF_R(26) TF_R(6)
  x0 += ks2; x1 += k0 + 5u;
#undef TF_R
  o0 = x0; o1 = x1;
}

__device__ __forceinline__ uint32_t rb32(uint32_t k0, uint32_t k1, uint32_t idx) {
  uint32_t a, b;
  tf2x32(k0, k1, 0u, idx, a, b);
  return a ^ b;
}

__device__ __forceinline__ float neg_log_unif(uint32_t bits) {
  float u = __uint_as_float((bits >> 9) | 0x3f800000u) - 1.0f;
  u = fmaxf(u, 1.17549435e-38f);
  return -__logf(u);
}

// bf16 split helpers (RNE)
__device__ __host__ __forceinline__ ushort f2bf(float f) {
  uint32_t x;
  __builtin_memcpy(&x, &f, 4);
  return (ushort)((x + 0x7fffu + ((x >> 16) & 1u)) >> 16);
}
__device__ __forceinline__ float bf2f(ushort h) {
  return __uint_as_float(((uint32_t)h) << 16);
}

// ---------------------------------------------------------------------------
// Convert conv2 weights -> tap-major split bf16: w2T[tap][oc][ic] hi/lo.
// ---------------------------------------------------------------------------
__global__ __launch_bounds__(256) void convert_w2(const float* __restrict__ w,
                                                  ushort* __restrict__ wh,
                                                  ushort* __restrict__ wl) {
  const int i = blockIdx.x * 256 + threadIdx.x;   // (tap*64 + oc)*32 + ic
  if (i < 51200) {
    const int ic = i & 31, oc = (i >> 5) & 63, tap = i >> 11;
    const float f = w[oc * 800 + ic * 25 + tap];
    const ushort h = f2bf(f);
    wh[i] = h;
    wl[i] = f2bf(f - bf2f(h));
  }
}

// ---------------------------------------------------------------------------
// Convert fc1 weights: [k][n] f32 -> transposed split bf16 [n][k] hi/lo.
// 32x32 LDS tile transpose; 1024 blocks.
// ---------------------------------------------------------------------------
__global__ __launch_bounds__(256) void convert_w1T(const float* __restrict__ w,
                                                   ushort* __restrict__ th,
                                                   ushort* __restrict__ tl) {
  __shared__ float tile[32][33];
  const int t = threadIdx.x;
  const int bi = blockIdx.x >> 5, bj = blockIdx.x & 31;   // k-tile, n-tile
  const int r = t >> 3, c = (t & 7) * 4;
  const float4 v = *(const float4*)&w[(size_t)(bi * 32 + r) * 1024 + bj * 32 + c];
  tile[r][c + 0] = v.x; tile[r][c + 1] = v.y;
  tile[r][c + 2] = v.z; tile[r][c + 3] = v.w;
  __syncthreads();
  const int n = bj * 32 + r;
  float u[4];
#pragma unroll
  for (int q = 0; q < 4; ++q) u[q] = tile[c + q][r];
  short4v hv, lv;
#pragma unroll
  for (int q = 0; q < 4; ++q) {
    const ushort h = f2bf(u[q]);
    hv[q] = (short)h;
    lv[q] = (short)f2bf(u[q] - bf2f(h));
  }
  *(short4v*)&th[(size_t)n * 1024 + bi * 32 + c] = hv;
  *(short4v*)&tl[(size_t)n * 1024 + bi * 32 + c] = lv;
}

// ---------------------------------------------------------------------------
// Kernel A: conv1(5x5)+pool on VALU (split-written), conv2 as tap-major
// split-bf16 MFMA (25 taps x K=32), pool, split bf16 output.
// One image per block, 256 threads. LDS ~33.7KB -> 4 blocks/CU.
// ---------------------------------------------------------------------------
__global__ __launch_bounds__(256, 4) void conv_fused(
    const float* __restrict__ aimg, const float* __restrict__ bimg,
    const float* __restrict__ w1, const float* __restrict__ b1,
    const ushort* __restrict__ w2h, const ushort* __restrict__ w2l,
    const float* __restrict__ b2,
    ushort* __restrict__ p2h, ushort* __restrict__ p2l, int B) {
  // union: phase1 {img 784f + w1s 800f = 6336B} | phase2 {whs/wls 10240B}
  //      | phase3 {ob 1024f = 4096B}
  __shared__ __align__(16) char smem[10240];
  __shared__ ushort buf1h[144 * 40];   // conv1 out, split hi: [pix][ic] pad40
  __shared__ ushort buf1l[144 * 40];
  __shared__ float b1s[32];
  __shared__ float b2s[64];

  float* img = (float*)smem;            // [784]
  float* w1s = img + 784;               // [800]
  ushort* whs = (ushort*)smem;          // [64][40] per-tap weights hi
  ushort* wls = whs + 64 * 40;          // lo
  float* ob = (float*)smem;             // [1024] epilogue staging

  const int t = threadIdx.x;
  const int im = blockIdx.x;
  const float* src = (im < B) ? (aimg + (size_t)im * 784)
                              : (bimg + (size_t)(im - B) * 784);
  for (int i = t; i < 784; i += 256) img[i] = src[i];
  for (int i = t; i < 800; i += 256) w1s[i] = w1[i];
  if (t < 32) b1s[t] = b1[t];
  if (t >= 64 && t < 128) b2s[t - 64] = b2[t - 64];
  __syncthreads();

  // ---- conv1 + pool: thread t -> ic=t>>3 (32), sub=t&7; 18 pooled px each.
  // Writes split bf16 into transposed layout buf1[pix][ic].
  {
    const int ic = t >> 3, sub = t & 7;
    float w[25];
#pragma unroll
    for (int k = 0; k < 25; ++k) w[k] = w1s[ic * 25 + k];
    const float bias = b1s[ic];
#pragma unroll 1
    for (int j = 0; j < 18; ++j) {
      const int p = sub + (j << 3);          // 0..143
      const int ph = p / 12, pw = p - ph * 12;
      const int y0 = ph << 1, x0 = pw << 1;
      float patch[36];
#pragma unroll
      for (int r = 0; r < 6; ++r)
#pragma unroll
        for (int c = 0; c < 6; ++c)
          patch[r * 6 + c] = img[(y0 + r) * 28 + x0 + c];
      float m = -3.0e38f;
#pragma unroll
      for (int dy = 0; dy < 2; ++dy)
#pragma unroll
        for (int dx = 0; dx < 2; ++dx) {
          float acc = 0.f;
#pragma unroll
          for (int kh = 0; kh < 5; ++kh)
#pragma unroll
            for (int kw = 0; kw < 5; ++kw)
              acc += w[kh * 5 + kw] * patch[(dy + kh) * 6 + (dx + kw)];
          m = fmaxf(m, acc);
        }
      const float fv = m + bias;
      const ushort h = f2bf(fv);
      buf1h[p * 40 + ic] = h;
      buf1l[p * 40 + ic] = f2bf(fv - bf2f(h));
    }
  }

  // ---- conv2: tap-major MFMA. Wave grid 2x2: wm=px-half, wn=oc-half.
  const int l = t & 63, wv = t >> 6;
  const int wm = wv >> 1, wn = wv & 1;
  const int ii = l & 15, gi = l >> 4;
  const int ocs = t >> 2, qq = t & 3;        // weight staging mapping

  // A-row pixel decomposition (px = 32*wm + 16*mt + ii)
  const int px0 = 32 * wm + ii, px1 = px0 + 16;
  const int ra0 = (px0 >> 3) * 12 + (px0 & 7);   // pix at tap(0,0)
  const int ra1 = (px1 >> 3) * 12 + (px1 & 7);

  f32x4 acc[2][2];
#pragma unroll
  for (int a = 0; a < 2; ++a)
#pragma unroll
    for (int b = 0; b < 2; ++b) acc[a][b] = (f32x4){0.f, 0.f, 0.f, 0.f};

  // prefetch tap 0 weights to regs
  short8 wgh = *(const short8*)&w2h[ocs * 32 + qq * 8];
  short8 wgl = *(const short8*)&w2l[ocs * 32 + qq * 8];

#pragma unroll 1
  for (int tap = 0; tap < 25; ++tap) {
    __syncthreads();   // prev frag reads done (tap0: conv1 img reads done)
    *(short8*)&whs[ocs * 40 + qq * 8] = wgh;
    *(short8*)&wls[ocs * 40 + qq * 8] = wgl;
    __syncthreads();
    const int ntap = (tap < 24) ? tap + 1 : 0;
    wgh = *(const short8*)&w2h[(ntap * 64 + ocs) * 32 + qq * 8];
    wgl = *(const short8*)&w2l[(ntap * 64 + ocs) * 32 + qq * 8];

    const int kh = (tap * 205) >> 10;        // tap/5
    const int kw = tap - kh * 5;
    const int pb = kh * 12 + kw;
    const short8 ah0 = *(const short8*)&buf1h[(ra0 + pb) * 40 + 8 * gi];
    const short8 al0 = *(const short8*)&buf1l[(ra0 + pb) * 40 + 8 * gi];
    const short8 ah1 = *(const short8*)&buf1h[(ra1 + pb) * 40 + 8 * gi];
    const short8 al1 = *(const short8*)&buf1l[(ra1 + pb) * 40 + 8 * gi];
    const short8 bh0 = *(const short8*)&whs[(32 * wn + ii) * 40 + 8 * gi];
    const short8 bl0 = *(const short8*)&wls[(32 * wn + ii) * 40 + 8 * gi];
    const short8 bh1 = *(const short8*)&whs[(32 * wn + 16 + ii) * 40 + 8 * gi];
    const short8 bl1 = *(const short8*)&wls[(32 * wn + 16 + ii) * 40 + 8 * gi];

    acc[0][0] = __builtin_amdgcn_mfma_f32_16x16x32_bf16(ah0, bh0, acc[0][0], 0, 0, 0);
    acc[0][0] = __builtin_amdgcn_mfma_f32_16x16x32_bf16(al0, bh0, acc[0][0], 0, 0, 0);
    acc[0][0] = __builtin_amdgcn_mfma_f32_16x16x32_bf16(ah0, bl0, acc[0][0], 0, 0, 0);
    acc[0][1] = __builtin_amdgcn_mfma_f32_16x16x32_bf16(ah0, bh1, acc[0][1], 0, 0, 0);
    acc[0][1] = __builtin_amdgcn_mfma_f32_16x16x32_bf16(al0, bh1, acc[0][1], 0, 0, 0);
    acc[0][1] = __builtin_amdgcn_mfma_f32_16x16x32_bf16(ah0, bl1, acc[0][1], 0, 0, 0);
    acc[1][0] = __builtin_amdgcn_mfma_f32_16x16x32_bf16(ah1, bh0, acc[1][0], 0, 0, 0);
    acc[1][0] = __builtin_amdgcn_mfma_f32_16x16x32_bf16(al1, bh0, acc[1][0], 0, 0, 0);
    acc[1][0] = __builtin_amdgcn_mfma_f32_16x16x32_bf16(ah1, bl0, acc[1][0], 0, 0, 0);
    acc[1][1] = __builtin_amdgcn_mfma_f32_16x16x32_bf16(ah1, bh1, acc[1][1], 0, 0, 0);
    acc[1][1] = __builtin_amdgcn_mfma_f32_16x16x32_bf16(al1, bh1, acc[1][1], 0, 0, 0);
    acc[1][1] = __builtin_amdgcn_mfma_f32_16x16x32_bf16(ah1, bl1, acc[1][1], 0, 0, 0);
  }
  __syncthreads();   // frag reads done before ob overwrites whs region

  // pool 2x2 + bias -> ob[oc*16 + ph*4 + pw]
#pragma unroll
  for (int mt = 0; mt < 2; ++mt)
#pragma unroll
    for (int nt = 0; nt < 2; ++nt)
#pragma unroll
      for (int j = 0; j < 2; ++j) {
        const float hm = fmaxf(acc[mt][nt][2 * j], acc[mt][nt][2 * j + 1]);
        const float vm = fmaxf(hm, __shfl_xor(hm, 32));
        if (gi < 2) {
          const int oc = 32 * wn + 16 * nt + ii;
          ob[oc * 16 + (2 * wm + mt) * 4 + 2 * gi + j] = vm + b2s[oc];
        }
      }
  __syncthreads();

  // split bf16 output (feeds fc1 MFMA directly)
  const float4 v = *(const float4*)&ob[4 * t];
  short4v hv, lv;
  const float* vp = (const float*)&v;
#pragma unroll
  for (int q = 0; q < 4; ++q) {
    const ushort h = f2bf(vp[q]);
    hv[q] = (short)h;
    lv[q] = (short)f2bf(vp[q] - bf2f(h));
  }
  *(short4v*)&p2h[(size_t)im * 1024 + 4 * t] = hv;
  *(short4v*)&p2l[(size_t)im * 1024 + 4 * t] = lv;
}

// ---------------------------------------------------------------------------
// Kernel C: fc1 as split-bf16 MFMA: out = relu(A[8192,1024] @ W[1024,1024] + b)
// 128x128 tile, BK=32, 4 waves in 2x2 grid, 16 16x16 D-tiles/wave, 3-pass.
// ---------------------------------------------------------------------------
__global__ __launch_bounds__(256, 2) void fc1_mfma(
    const ushort* __restrict__ ah_g, const ushort* __restrict__ al_g,
    const ushort* __restrict__ wh_g, const ushort* __restrict__ wl_g,
    const float* __restrict__ bias, float* __restrict__ out) {
  __shared__ ushort Ah[128 * 40], Al[128 * 40], Bh[128 * 40], Bl[128 * 40];
  const int t = threadIdx.x;
  const int bx = blockIdx.x & 7, by = blockIdx.x >> 3;
  const int m0 = by * 128, n0 = bx * 128;
  const int l = t & 63, wv = t >> 6;
  const int wm = wv >> 1, wn = wv & 1;
  const int ii = l & 15, gi = l >> 4;
  const int sr = t >> 1, sk = (t & 1) * 16;    // stage: row, k-offset

  f32x4 acc[4][4];
#pragma unroll
  for (int a = 0; a < 4; ++a)
#pragma unroll
    for (int b = 0; b < 4; ++b) acc[a][b] = (f32x4){0.f, 0.f, 0.f, 0.f};

  float bias_r[4];
#pragma unroll
  for (int nt = 0; nt < 4; ++nt)
    bias_r[nt] = bias[n0 + 64 * wn + 16 * nt + ii];

  // prologue: load k0=0 tiles to regs
  short8 ga0 = *(const short8*)&ah_g[(size_t)(m0 + sr) * 1024 + sk];
  short8 ga1 = *(const short8*)&ah_g[(size_t)(m0 + sr) * 1024 + sk + 8];
  short8 ga2 = *(const short8*)&al_g[(size_t)(m0 + sr) * 1024 + sk];
  short8 ga3 = *(const short8*)&al_g[(size_t)(m0 + sr) * 1024 + sk + 8];
  short8 gb0 = *(const short8*)&wh_g[(size_t)(n0 + sr) * 1024 + sk];
  short8 gb1 = *(const short8*)&wh_g[(size_t)(n0 + sr) * 1024 + sk + 8];
  short8 gb2 = *(const short8*)&wl_g[(size_t)(n0 + sr) * 1024 + sk];
  short8 gb3 = *(const short8*)&wl_g[(size_t)(n0 + sr) * 1024 + sk + 8];

#pragma unroll 1
  for (int k0 = 0; k0 < 1024; k0 += 32) {
    __syncthreads();
    *(short8*)&Ah[sr * 40 + sk] = ga0;
    *(short8*)&Ah[sr * 40 + sk + 8] = ga1;
    *(short8*)&Al[sr * 40 + sk] = ga2;
    *(short8*)&Al[sr * 40 + sk + 8] = ga3;
    *(short8*)&Bh[sr * 40 + sk] = gb0;
    *(short8*)&Bh[sr * 40 + sk + 8] = gb1;
    *(short8*)&Bl[sr * 40 + sk] = gb2;
    *(short8*)&Bl[sr * 40 + sk + 8] = gb3;
    __syncthreads();
    const int kn = (k0 + 32 < 1024) ? k0 + 32 : 0;   // prefetch next (wraps)
    ga0 = *(const short8*)&ah_g[(size_t)(m0 + sr) * 1024 + kn + sk];
    ga1 = *(const short8*)&ah_g[(size_t)(m0 + sr) * 1024 + kn + sk + 8];
    ga2 = *(const short8*)&al_g[(size_t)(m0 + sr) * 1024 + kn + sk];
    ga3 = *(const short8*)&al_g[(size_t)(m0 + sr) * 1024 + kn + sk + 8];
    gb0 = *(const short8*)&wh_g[(size_t)(n0 + sr) * 1024 + kn + sk];
    gb1 = *(const short8*)&wh_g[(size_t)(n0 + sr) * 1024 + kn + sk + 8];
    gb2 = *(const short8*)&wl_g[(size_t)(n0 + sr) * 1024 + kn + sk];
    gb3 = *(const short8*)&wl_g[(size_t)(n0 + sr) * 1024 + kn + sk + 8];

    short8 bh[4], bl[4];
#pragma unroll
    for (int nt = 0; nt < 4; ++nt) {
      bh[nt] = *(const short8*)&Bh[(64 * wn + 16 * nt + ii) * 40 + 8 * gi];
      bl[nt] = *(const short8*)&Bl[(64 * wn + 16 * nt + ii) * 40 + 8 * gi];
    }
#pragma unroll
    for (int mt = 0; mt < 4; ++mt) {
      const short8 ah = *(const short8*)&Ah[(64 * wm + 16 * mt + ii) * 40 + 8 * gi];
      const short8 al = *(const short8*)&Al[(64 * wm + 16 * mt + ii) * 40 + 8 * gi];
#pragma unroll
      for (int nt = 0; nt < 4; ++nt) {
        acc[mt][nt] = __builtin_amdgcn_mfma_f32_16x16x32_bf16(ah, bh[nt], acc[mt][nt], 0, 0, 0);
        acc[mt][nt] = __builtin_amdgcn_mfma_f32_16x16x32_bf16(al, bh[nt], acc[mt][nt], 0, 0, 0);
        acc[mt][nt] = __builtin_amdgcn_mfma_f32_16x16x32_bf16(ah, bl[nt], acc[mt][nt], 0, 0, 0);
      }
    }
  }

  // epilogue: bias + relu, scalar stores (16 lanes x 4B = 64B runs)
#pragma unroll
  for (int mt = 0; mt < 4; ++mt) {
    const int rbase = m0 + 64 * wm + 16 * mt + 4 * gi;
#pragma unroll
    for (int nt = 0; nt < 4; ++nt) {
      const int c = n0 + 64 * wn + 16 * nt + ii;
#pragma unroll
      for (int reg = 0; reg < 4; ++reg)
        out[(size_t)(rbase + reg) * 1024 + c] =
            fmaxf(acc[mt][nt][reg] + bias_r[nt], 0.f);
    }
  }
}

// ---------------------------------------------------------------------------
// Kernel D: fc2 (1024->10) + softmax. One wave per row.
// ---------------------------------------------------------------------------
__global__ __launch_bounds__(64) void fc2_softmax(const float* __restrict__ X,
                                                  const float* __restrict__ W,
                                                  const float* __restrict__ bias,
                                                  float* __restrict__ distrs,
                                                  float* __restrict__ invp) {
  const int row = blockIdx.x, l = threadIdx.x;
  const float* x = X + (size_t)row * 1024;
  float acc[10];
#pragma unroll
  for (int c = 0; c < 10; ++c) acc[c] = 0.f;
  for (int k = l; k < 1024; k += 64) {
    const float xv = x[k];
    const float* wr = W + (size_t)k * 10;
#pragma unroll
    for (int c = 0; c < 10; ++c) acc[c] += xv * wr[c];
  }
#pragma unroll
  for (int c = 0; c < 10; ++c) {
    float v = acc[c];
#pragma unroll
    for (int off = 32; off > 0; off >>= 1) v += __shfl_xor(v, off, 64);
    acc[c] = v;
  }
  float z[10], m = -3.0e38f;
#pragma unroll
  for (int c = 0; c < 10; ++c) { z[c] = acc[c] + bias[c]; m = fmaxf(m, z[c]); }
  float s = 0.f, e[10];
#pragma unroll
  for (int c = 0; c < 10; ++c) { e[c] = __expf(z[c] - m); s += e[c]; }
  if (l < 10) {
    distrs[(size_t)row * 10 + l] = e[l] / s;
    invp[(size_t)row * 10 + l] = s / e[l];
  }
}

// ---------------------------------------------------------------------------
// Kernel E: threefry categorical + masked hist + per-row MSE partials.
// ---------------------------------------------------------------------------
__global__ __launch_bounds__(512) void sample_hist_mse(
    const float* __restrict__ distrs, const float* __restrict__ invp,
    const int* __restrict__ y, const int* __restrict__ nsamp,
    float* __restrict__ out, int B,
    uint32_t ka0, uint32_t ka1, uint32_t kb0, uint32_t kb1) {
  const int brow = blockIdx.x, tid = threadIdx.x;
  __shared__ float ipa[10], ipb[10], part[10];
  __shared__ int ha[10], tot;
  if (tid < 10) { ipa[tid] = invp[(size_t)brow * 10 + tid]; ha[tid] = 0; }
  else if (tid < 20) ipb[tid - 10] = invp[(size_t)(B + brow) * 10 + (tid - 10)];
  else if (tid == 20) tot = 0;
  __syncthreads();
  const int yy = y[brow];
  const int S = nsamp[0];
  for (int s0 = 0; s0 < S; s0 += 512) {
    const int s = s0 + tid;
    if (s >= S) break;
    const uint32_t base = ((uint32_t)s * (uint32_t)B + (uint32_t)brow) * 10u;
    float bestA = __builtin_inff(), bestB = __builtin_inff();
    int as = 0, bs = 0;
#pragma unroll
    for (int c = 0; c < 10; ++c) {
      const float va = neg_log_unif(rb32(ka0, ka1, base + (uint32_t)c)) * ipa[c];
      if (va < bestA) { bestA = va; as = c; }
      const float vb = neg_log_unif(rb32(kb0, kb1, base + (uint32_t)c)) * ipb[c];
      if (vb < bestB) { bestB = vb; bs = c; }
    }
    if (bs == yy && as >= bs) { atomicAdd(&ha[as], 1); atomicAdd(&tot, 1); }
  }
  __syncthreads();
  if (tid < 10) {
    const int tc = tot;
    const float denom = fmaxf((float)tc, 1.0f);
    const float ap = (tc > 0) ? (float)ha[tid] / denom : 0.0f;
    const float bp = (tc > 0 && tid == yy) ? ((float)tc / denom) : 0.0f;
    const float da = distrs[(size_t)brow * 10 + tid] - ap;
    const float db = distrs[(size_t)(B + brow) * 10 + tid] - bp;
    part[tid] = da * da + db * db;
  }
  __syncthreads();
  if (tid == 0) {
    float sum = 0.f;
#pragma unroll
    for (int i = 0; i < 10; ++i) sum += part[i];
    atomicAdd(out, sum);
  }
}

__global__ void finalize_mean(float* out, float n) { out[0] = out[0] / n; }

// ---------------------------------------------------------------------------
extern "C" void kernel_launch(void* const* d_in, const int* in_sizes, int n_in,
                              void* d_out, int out_size, void* d_ws, size_t ws_size,
                              hipStream_t stream) {
  (void)n_in; (void)out_size; (void)ws_size;
  const float* a_imgs = (const float*)d_in[0];
  const float* b_imgs = (const float*)d_in[1];
  const float* c1w = (const float*)d_in[2];
  const float* c1b = (const float*)d_in[3];
  const float* c2w = (const float*)d_in[4];
  const float* c2b = (const float*)d_in[5];
  const float* f1w = (const float*)d_in[6];
  const float* f1b = (const float*)d_in[7];
  const float* f2w = (const float*)d_in[8];
  const float* f2b = (const float*)d_in[9];
  const int* y = (const int*)d_in[10];
  const int* nsamp = (const int*)d_in[11];

  const int B = in_sizes[0] / 784;   // 4096
  const int R = 2 * B;               // 8192 images

  char* ws = (char*)d_ws;
  ushort* p2h   = (ushort*)ws;                          // [8192*1024] 16.78MB
  ushort* p2l   = p2h + (size_t)R * 1024;               // 16.78MB
  float* fc1out = (float*)(p2l + (size_t)R * 1024);     // 33.55MB
  ushort* f1wTh = (ushort*)(fc1out + (size_t)R * 1024); // 2.10MB
  ushort* f1wTl = f1wTh + 1024 * 1024;                  // 2.10MB
  ushort* w2hT  = f1wTl + 1024 * 1024;                  // 102KB
  ushort* w2lT  = w2hT + 51200;                         // 102KB
  float* distrs = (float*)(w2lT + 51200);               // 328KB
  float* invp   = distrs + (size_t)R * 10;              // 328KB

  uint32_t ka0, ka1, kb0, kb1;
  tf2x32(0u, 42u, 0u, 0u, ka0, ka1);
  tf2x32(0u, 42u, 0u, 1u, kb0, kb1);

  hipMemsetAsync(d_out, 0, sizeof(float), stream);
  convert_w2<<<200, 256, 0, stream>>>(c2w, w2hT, w2lT);
  convert_w1T<<<1024, 256, 0, stream>>>(f1w, f1wTh, f1wTl);
  conv_fused<<<R, 256, 0, stream>>>(a_imgs, b_imgs, c1w, c1b, w2hT, w2lT, c2b,
                                    p2h, p2l, B);
  fc1_mfma<<<512, 256, 0, stream>>>(p2h, p2l, f1wTh, f1wTl, f1b, fc1out);
  fc2_softmax<<<R, 64, 0, stream>>>(fc1out, f2w, f2b, distrs, invp);
  sample_hist_mse<<<B, 512, 0, stream>>>(distrs, invp, y, nsamp, (float*)d_out, B,
                                         ka0, ka1, kb0, kb1);
  finalize_mean<<<1, 1, 0, stream>>>((float*)d_out, (float)R * 10.0f);
}